// Round 4
// baseline (1652.806 us; speedup 1.0000x reference)
//
#include <hip/hip_runtime.h>
#include <hip/hip_bf16.h>
#include <type_traits>

#define LAYERS 4
#define D      768
#define FF     3072
#define NH     12
#define HD     64
#define SEQ    4096
#define BATCH  4
#define WIN    128
#define NC     (SEQ / WIN)        // 32
#define NTOK   (BATCH * SEQ)      // 16384

using bf16 = __hip_bfloat16;
typedef short short8 __attribute__((ext_vector_type(8)));
typedef short short4v __attribute__((ext_vector_type(4)));
typedef float floatx4 __attribute__((ext_vector_type(4)));

__device__ __forceinline__ float b2f(unsigned short u) {
    return __uint_as_float(((unsigned)u) << 16);
}
__device__ __forceinline__ short f2bs(float f) {
    union { bf16 h; short s; } u; u.h = __float2bfloat16(f); return u.s;
}
__device__ __forceinline__ void st_cvt(float* p, float v) { *p = v; }
__device__ __forceinline__ void st_cvt(bf16* p, float v) { *p = __float2bfloat16(v); }

// async global->LDS, 16B per lane; LDS dest is wave-uniform base + lane*16
__device__ __forceinline__ void gl_lds16(const void* g, void* l) {
    __builtin_amdgcn_global_load_lds(
        (const __attribute__((address_space(1))) void*)g,
        (__attribute__((address_space(3))) void*)l, 16, 0, 0);
}

#define SB0   __builtin_amdgcn_sched_barrier(0)
#define BAR   __builtin_amdgcn_s_barrier()
#define VM4   asm volatile("s_waitcnt vmcnt(4)" ::: "memory")
#define VM0   asm volatile("s_waitcnt vmcnt(0)" ::: "memory")
#define SP1   __builtin_amdgcn_s_setprio(1)
#define SP0   __builtin_amdgcn_s_setprio(0)

// ---------------- f32 -> bf16 bulk convert (8 elems/thread) ----------------------
__global__ __launch_bounds__(256)
void cvt_f32_bf16(const float* __restrict__ src, bf16* __restrict__ dst)
{
    const int i = (blockIdx.x * 256 + threadIdx.x) * 8;
    const float4 a0 = *(const float4*)(src + i);
    const float4 a1 = *(const float4*)(src + i + 4);
    short8 p = { f2bs(a0.x), f2bs(a0.y), f2bs(a0.z), f2bs(a0.w),
                 f2bs(a1.x), f2bs(a1.y), f2bs(a1.z), f2bs(a1.w) };
    *(short8*)((short*)dst + i) = p;
}

// ---------------- weight transpose+convert: W[K][N] f32 -> WT[N][K] bf16 ----------
__global__ __launch_bounds__(256)
void transpose_cvt(const float* __restrict__ src, bf16* __restrict__ dst, int K, int N)
{
    __shared__ float t[32][33];
    const int n0 = blockIdx.x * 32, k0 = blockIdx.y * 32;
    const int tx = threadIdx.x & 31, ty = threadIdx.x >> 5;   // ty 0..7
    #pragma unroll
    for (int r = 0; r < 4; ++r)
        t[ty + 8 * r][tx] = src[(size_t)(k0 + ty + 8 * r) * N + n0 + tx];
    __syncthreads();
    #pragma unroll
    for (int r = 0; r < 4; ++r)
        dst[(size_t)(n0 + ty + 8 * r) * K + k0 + tx] = __float2bfloat16(t[tx][ty + 8 * r]);
}

// ================= 256x256 8-phase GEMM (T2+T3+T4+T5) =============================
// 512 threads = 8 waves (2M x 4N); per-wave output 128x64, half-interleaved.
// LDS 128 KiB dynamic, XOR-swizzled (byte ^= (row&7)<<4) both sides (rule #21).
// SINGLE barrier per phase (phase-end). Safety: every ds_read issued in phase p
// is consumed by p's own MFMA (per-operand lgkmcnt), every gl_lds write targets
// a slot whose last read completed >=2 phase-end barriers earlier, and VM4 at
// P4/P8 (in-order vmcnt) makes writes visible before the releasing barrier.
// The 2 waves/SIMD now stagger inside a phase: one issues ds_reads while the
// other runs MFMA -> read latency and stage-issue hide under the matrix pipe.
template<int OMODE, int RELU>
__global__ __launch_bounds__(512, 2)
void gemm8(const bf16* __restrict__ A, const bf16* __restrict__ Wt,
           const float* __restrict__ b0, const float* __restrict__ b1p,
           const float* __restrict__ b2p, bf16* __restrict__ C,
           int K, int N)
{
    extern __shared__ char ldsc[];
    const int tid  = threadIdx.x;
    const int lane = tid & 63;
    const int wave = tid >> 6;
    const int quad = lane >> 4, l16 = lane & 15;
    const int wm = wave >> 2, wn = wave & 3;          // 2M x 4N wave grid

    // bijective XCD swizzle on M (gridDim.x == 64)
    const int bx  = blockIdx.x;
    const int bxs = (bx & 7) * 8 + (bx >> 3);
    const int row0 = bxs * 256;
    const int col0 = blockIdx.y * 256;

    // ---- staging address precompute (2 gl_lds per stage per thread) ----
    const int lin0 = wave * 1024 + lane * 16;         // e=0 dest byte in slot
    const int lin1 = 8192 + wave * 1024 + lane * 16;  // e=1
    const int rl0 = lin0 >> 7, rl1 = lin1 >> 7;       // local row 0..127
    const int so0 = (lin0 & 127) ^ ((rl0 & 7) << 4);  // pre-swizzled src offset
    const int so1 = (lin1 & 127) ^ ((rl1 & 7) << 4);
    const char* agl0 = (const char*)A  + 2 * ((size_t)(row0 + rl0) * K) + so0;
    const char* agl1 = (const char*)A  + 2 * ((size_t)(row0 + rl1) * K) + so1;
    const char* bgl0 = (const char*)Wt + 2 * ((size_t)(col0 + rl0) * K) + so0;
    const char* bgl1 = (const char*)Wt + 2 * ((size_t)(col0 + rl1) * K) + so1;
    const size_t hstr = (size_t)128 * K * 2;          // +128 rows

#define STA(d,h,kt) do { \
    gl_lds16(agl0 + ((h) ? hstr : 0) + (size_t)(kt) * 128, ldsc + ((d)*2+(h))*16384 + lin0); \
    gl_lds16(agl1 + ((h) ? hstr : 0) + (size_t)(kt) * 128, ldsc + ((d)*2+(h))*16384 + lin1); } while (0)
#define STB(d,h,kt) do { \
    gl_lds16(bgl0 + ((h) ? hstr : 0) + (size_t)(kt) * 128, ldsc + 65536 + ((d)*2+(h))*16384 + lin0); \
    gl_lds16(bgl1 + ((h) ? hstr : 0) + (size_t)(kt) * 128, ldsc + 65536 + ((d)*2+(h))*16384 + lin1); } while (0)

    // ---- fragment read precompute (XOR-swizzled ds_read_b128) ----
    const int arow  = wm * 64 + l16;
    const int abase = arow * 128;
    const int sA    = (arow & 7) << 4;
    const int aof0  = (quad * 16) ^ sA;
    const int aof1  = (64 + quad * 16) ^ sA;
    const int brow  = wn * 32 + l16;
    const int bbase = brow * 128;
    const int sB    = (brow & 7) << 4;
    const int bof0  = (quad * 16) ^ sB;
    const int bof1  = (64 + quad * 16) ^ sB;

    short8 af[4][2], bf0[2][2], bf1[2][2];
    floatx4 acc[2][2][4][2];
    const floatx4 zero = {0.f, 0.f, 0.f, 0.f};
    #pragma unroll
    for (int a = 0; a < 2; ++a)
        #pragma unroll
        for (int b = 0; b < 2; ++b)
            #pragma unroll
            for (int m = 0; m < 4; ++m)
                #pragma unroll
                for (int n = 0; n < 2; ++n) acc[a][b][m][n] = zero;

#define LDA(slot) do { const char* ab_ = ldsc + (slot)*16384 + abase; \
    _Pragma("unroll") for (int m_ = 0; m_ < 4; ++m_) { \
        af[m_][0] = *(const short8*)(ab_ + m_*2048 + aof0); \
        af[m_][1] = *(const short8*)(ab_ + m_*2048 + aof1); } } while (0)
#define LDB(slot, BF) do { const char* bb_ = ldsc + 65536 + (slot)*16384 + bbase; \
    _Pragma("unroll") for (int n_ = 0; n_ < 2; ++n_) { \
        BF[n_][0] = *(const short8*)(bb_ + n_*2048 + bof0); \
        BF[n_][1] = *(const short8*)(bb_ + n_*2048 + bof1); } } while (0)
#define MM(mh, nh, BF) do { \
    _Pragma("unroll") for (int m_ = 0; m_ < 4; ++m_) \
    _Pragma("unroll") for (int n_ = 0; n_ < 2; ++n_) { \
        acc[mh][nh][m_][n_] = __builtin_amdgcn_mfma_f32_16x16x32_bf16(af[m_][0], BF[n_][0], acc[mh][nh][m_][n_], 0, 0, 0); \
        acc[mh][nh][m_][n_] = __builtin_amdgcn_mfma_f32_16x16x32_bf16(af[m_][1], BF[n_][1], acc[mh][nh][m_][n_], 0, 0, 0); } } while (0)

    const int nkt   = K >> 6;    // 64-wide K-tiles
    const int niter = K >> 7;    // 2 tiles per iteration

    // ---- prologue: t0 full -> buf0, t1 A0/B0 -> buf1 ----
    STA(0,0,0); STB(0,0,0); STA(0,1,0); STB(0,1,0);
    STA(1,0,1); STB(1,0,1);
    VM4; SB0; BAR; SB0;

    for (int i = 0; i < niter; ++i) {
        const int k1 = 2*i + 1;
        const int k2 = (2*i + 2 < nkt) ? 2*i + 2 : nkt - 1;
        const int k3 = (2*i + 3 < nkt) ? 2*i + 3 : nkt - 1;
        // P1: Q(0,0) of buf0 | stage A1(t+1)->buf1
        LDA(0); LDB(0, bf0); STA(1,1,k1);
        SP1; MM(0,0,bf0); SP0; SB0; BAR; SB0;
        // P2: Q(0,1) | stage B1(t+1)->buf1
        LDB(1, bf1); STB(1,1,k1);
        SP1; MM(0,1,bf1); SP0; SB0; BAR; SB0;
        // P3: Q(1,0) | stage A0(t+2)->buf0
        LDA(1); STA(0,0,k2);
        SP1; MM(1,0,bf0); SP0; SB0; BAR; SB0;
        // P4: Q(1,1) | stage B0(t+2)->buf0 | vmcnt(4)
        STB(0,0,k2);
        SP1; MM(1,1,bf1); SP0; VM4; SB0; BAR; SB0;
        // P5: Q(0,0) of buf1 | stage A1(t+2)->buf0
        LDA(2); LDB(2, bf0); STA(0,1,k2);
        SP1; MM(0,0,bf0); SP0; SB0; BAR; SB0;
        // P6: Q(0,1) | stage B1(t+2)->buf0
        LDB(3, bf1); STB(0,1,k2);
        SP1; MM(0,1,bf1); SP0; SB0; BAR; SB0;
        // P7: Q(1,0) | stage A0(t+3)->buf1
        LDA(3); STA(1,0,k3);
        SP1; MM(1,0,bf0); SP0; SB0; BAR; SB0;
        // P8: Q(1,1) | stage B0(t+3)->buf1 | vmcnt(4)
        STB(1,0,k3);
        SP1; MM(1,1,bf1); SP0; VM4; SB0; BAR; SB0;
    }
    VM0;   // drain clamped prefetches before epilogue

#undef STA
#undef STB
#undef LDA
#undef LDB
#undef MM

    // ---- epilogue ----
    constexpr size_t QEc = (size_t)BATCH * NH * SEQ * HD;
    int sel = 0;
    const float* bptr = b0;
    float scl = 1.0f;
    int ccb = col0;
    if constexpr (OMODE == 3) {
        sel  = blockIdx.y / 3;                 // 0=Q 1=K 2=V (uniform per block)
        bptr = (sel == 0) ? b0 : (sel == 1) ? b1p : b2p;
        scl  = (sel == 0) ? 0.125f : 1.0f;
        ccb  = col0 - sel * 768;
    }
    #pragma unroll
    for (int mh = 0; mh < 2; ++mh)
    #pragma unroll
    for (int nh = 0; nh < 2; ++nh)
    #pragma unroll
    for (int n = 0; n < 2; ++n) {
        const int c  = ccb + nh * 128 + wn * 32 + n * 16 + l16;
        const float bvv = bptr[c];
        #pragma unroll
        for (int m = 0; m < 4; ++m) {
            const int rr0 = row0 + mh * 128 + wm * 64 + m * 16 + quad * 4;
            if constexpr (OMODE == 3) {
                if (sel == 2) {
                    short4v pack;
                    #pragma unroll
                    for (int r = 0; r < 4; ++r)
                        pack[r] = f2bs(acc[mh][nh][m][n][r] + bvv);
                    const int b_ = rr0 >> 12, s_ = rr0 & (SEQ - 1);
                    const int h_ = c >> 6, d_ = c & (HD - 1);
                    bf16* Cv = C + 2 * QEc;
                    *(short4v*)&Cv[(((size_t)(b_ * NH + h_)) * HD + d_) * SEQ + s_] = pack;
                } else {
                    bf16* Cq = C + (size_t)sel * QEc;
                    #pragma unroll
                    for (int r = 0; r < 4; ++r) {
                        const float v = (acc[mh][nh][m][n][r] + bvv) * scl;
                        const int rr = rr0 + r;
                        const int b_ = rr >> 12, s_ = rr & (SEQ - 1);
                        const int h_ = c >> 6, d_ = c & (HD - 1);
                        Cq[(((size_t)(b_ * NH + h_)) * SEQ + s_) * HD + d_] = __float2bfloat16(v);
                    }
                }
            } else {
                #pragma unroll
                for (int r = 0; r < 4; ++r) {
                    float v = acc[mh][nh][m][n][r] + bvv;
                    if (RELU) v = fmaxf(v, 0.f);
                    C[(size_t)(rr0 + r) * N + c] = __float2bfloat16(v);
                }
            }
        }
    }
}

// ---------------- round-1 fast MFMA GEMM (fallback if dyn-LDS attr fails) ---------
template<int RELU, int OMODE>
__global__ __launch_bounds__(256)
void mfma_gemm_bf(const bf16* __restrict__ A, const bf16* __restrict__ Wt,
                  const float* __restrict__ bias, bf16* __restrict__ C,
                  int M, int N, int K, float scale)
{
    __shared__ __align__(16) short As[128 * 32];
    __shared__ __align__(16) short Bs[128 * 32];
    const int tid  = threadIdx.x;
    const int lane = tid & 63;
    const int wave = tid >> 6;
    const int quad = lane >> 4, l16 = lane & 15;
    const int mw = (wave >> 1) * 64, nw = (wave & 1) * 64;
    const int row0 = blockIdx.x * 128;
    const int col0 = blockIdx.y * 128;

    const unsigned short* Ag = (const unsigned short*)A;
    const unsigned short* Bg = (const unsigned short*)Wt;
    const int sr = lane >> 2;
    const int sc = (lane & 3) * 8;

    floatx4 acc[4][4];
    const floatx4 zero = {0.f, 0.f, 0.f, 0.f};
    #pragma unroll
    for (int i = 0; i < 4; ++i)
        #pragma unroll
        for (int j = 0; j < 4; ++j) acc[i][j] = zero;

    const size_t abase = (size_t)row0 * K;
    const size_t bbase = (size_t)col0 * K;

    for (int k0 = 0; k0 < K; k0 += 32) {
        __syncthreads();
        #pragma unroll
        for (int e = 0; e < 2; ++e) {
            const int seg = wave * 2 + e;
            const int r = seg * 16 + sr;
            gl_lds16(Ag + abase + (size_t)r * K + k0 + sc, &As[seg * 512]);
            gl_lds16(Bg + bbase + (size_t)r * K + k0 + sc, &Bs[seg * 512]);
        }
        __syncthreads();
        short8 af[4], bfr[4];
        #pragma unroll
        for (int i = 0; i < 4; ++i)
            af[i] = *(const short8*)&As[(mw + 16 * i + l16) * 32 + quad * 8];
        #pragma unroll
        for (int j = 0; j < 4; ++j)
            bfr[j] = *(const short8*)&Bs[(nw + 16 * j + l16) * 32 + quad * 8];
        #pragma unroll
        for (int i = 0; i < 4; ++i)
            #pragma unroll
            for (int j = 0; j < 4; ++j)
                acc[i][j] = __builtin_amdgcn_mfma_f32_16x16x32_bf16(af[i], bfr[j], acc[i][j], 0, 0, 0);
    }
    #pragma unroll
    for (int j = 0; j < 4; ++j) {
        const int c = col0 + nw + 16 * j + l16;
        const float bv = bias[c];
        #pragma unroll
        for (int i = 0; i < 4; ++i) {
            const int rr0 = row0 + mw + 16 * i + quad * 4;
            if constexpr (OMODE == 2) {
                short4v pack;
                #pragma unroll
                for (int r = 0; r < 4; ++r)
                    pack[r] = f2bs((acc[i][j][r] + bv) * scale);
                const int b_ = rr0 >> 12, s_ = rr0 & (SEQ - 1);
                const int h_ = c >> 6, d_ = c & (HD - 1);
                *(short4v*)&C[(((size_t)(b_ * NH + h_)) * HD + d_) * SEQ + s_] = pack;
            } else {
                #pragma unroll
                for (int r = 0; r < 4; ++r) {
                    float v = acc[i][j][r] + bv;
                    if (RELU) v = fmaxf(v, 0.f);
                    v *= scale;
                    const int rr = rr0 + r;
                    if constexpr (OMODE == 1) {
                        const int b_ = rr >> 12, s_ = rr & (SEQ - 1);
                        const int h_ = c >> 6, d_ = c & (HD - 1);
                        st_cvt(&C[(((size_t)(b_ * NH + h_)) * SEQ + s_) * HD + d_], v);
                    } else {
                        st_cvt(&C[(size_t)rr * N + c], v);
                    }
                }
            }
        }
    }
}

// ---------------- MFMA sliding-window flash attention ----------------------------
__global__ __launch_bounds__(256, 2)
void attn_mfma_kernel(const bf16* __restrict__ q, const bf16* __restrict__ k,
                      const bf16* __restrict__ v, bf16* __restrict__ out)
{
    __shared__ __align__(16) short Qs[128][72];     // [q][d]
    __shared__ __align__(16) short Ks[64][72];      // [key][d]
    __shared__ __align__(16) short Vs[64][72];      // [d][key]  (V^T)
    __shared__ __align__(16) short Ps[4][32][72];   // per-wave P [q][key]

    const int c = blockIdx.x, h = blockIdx.y, b = blockIdx.z;
    const int tid = threadIdx.x;
    const int wave = tid >> 6, lane = tid & 63;
    const int quad = lane >> 4, l16 = lane & 15;
    const int qbase = wave * 32;

    const unsigned short* qg = (const unsigned short*)q + ((size_t)(b * NH + h)) * SEQ * HD;
    const unsigned short* kg = (const unsigned short*)k + ((size_t)(b * NH + h)) * SEQ * HD;
    const unsigned short* vg = (const unsigned short*)v + ((size_t)(b * NH + h)) * HD * SEQ;

    #pragma unroll
    for (int e = 0; e < 4; ++e) {
        const int idx = tid + e * 256;
        const int row = idx >> 3, d0 = (idx & 7) * 8;
        *(uint4*)&Qs[row][d0] = *(const uint4*)(qg + (size_t)(c * WIN + row) * HD + d0);
    }

    floatx4 O[2][4];
    const floatx4 zero = {0.f, 0.f, 0.f, 0.f};
    float m_i[2][4], l_i[2][4];
    #pragma unroll
    for (int i = 0; i < 2; ++i)
        #pragma unroll
        for (int r = 0; r < 4; ++r) { m_i[i][r] = -1e30f; l_i[i][r] = 0.f; }
    #pragma unroll
    for (int i = 0; i < 2; ++i)
        #pragma unroll
        for (int dj = 0; dj < 4; ++dj) O[i][dj] = zero;

    for (int sl = 0; sl < 6; ++sl) {
        const int s0 = sl * 64;
        const int kpos0 = c * WIN - WIN + s0;
        if (kpos0 < 0 || kpos0 >= SEQ) continue;
        __syncthreads();
        #pragma unroll
        for (int e = 0; e < 2; ++e) {
            const int idx = tid + e * 256;
            const int row = idx >> 3, d0 = (idx & 7) * 8;
            *(uint4*)&Ks[row][d0] = *(const uint4*)(kg + (size_t)(kpos0 + row) * HD + d0);
            *(uint4*)&Vs[row][d0] = *(const uint4*)(vg + (size_t)row * SEQ + kpos0 + d0);
        }
        __syncthreads();
        short8 aq[2][2], bk2[4][2];
        #pragma unroll
        for (int i = 0; i < 2; ++i)
            #pragma unroll
            for (int hh = 0; hh < 2; ++hh)
                aq[i][hh] = *(const short8*)&Qs[qbase + 16 * i + l16][hh * 32 + quad * 8];
        #pragma unroll
        for (int j = 0; j < 4; ++j)
            #pragma unroll
            for (int hh = 0; hh < 2; ++hh)
                bk2[j][hh] = *(const short8*)&Ks[16 * j + l16][hh * 32 + quad * 8];
        floatx4 sc[2][4];
        #pragma unroll
        for (int i = 0; i < 2; ++i)
            #pragma unroll
            for (int j = 0; j < 4; ++j) {
                floatx4 t = __builtin_amdgcn_mfma_f32_16x16x32_bf16(aq[i][0], bk2[j][0], zero, 0, 0, 0);
                sc[i][j]  = __builtin_amdgcn_mfma_f32_16x16x32_bf16(aq[i][1], bk2[j][1], t, 0, 0, 0);
            }
        #pragma unroll
        for (int i = 0; i < 2; ++i) {
            #pragma unroll
            for (int r = 0; r < 4; ++r) {
                const int qq = qbase + 16 * i + quad * 4 + r;
                float sv[4];
                float mx = -1e30f;
                #pragma unroll
                for (int j = 0; j < 4; ++j) {
                    const int kj = s0 + 16 * j + l16;
                    const bool ok = (kj >= qq) && (kj <= qq + 2 * WIN);
                    const float s = ok ? sc[i][j][r] : -1e30f;
                    sv[j] = s;
                    mx = fmaxf(mx, s);
                }
                mx = fmaxf(mx, __shfl_xor(mx, 1));
                mx = fmaxf(mx, __shfl_xor(mx, 2));
                mx = fmaxf(mx, __shfl_xor(mx, 4));
                mx = fmaxf(mx, __shfl_xor(mx, 8));
                const float mn = fmaxf(m_i[i][r], mx);
                const float corr = __expf(m_i[i][r] - mn);
                m_i[i][r] = mn;
                float ps = 0.f;
                #pragma unroll
                for (int j = 0; j < 4; ++j) {
                    const float p = (sv[j] > -0.9e30f) ? __expf(sv[j] - mn) : 0.f;
                    ps += p;
                    Ps[wave][16 * i + quad * 4 + r][16 * j + l16] = f2bs(p);
                }
                ps += __shfl_xor(ps, 1);
                ps += __shfl_xor(ps, 2);
                ps += __shfl_xor(ps, 4);
                ps += __shfl_xor(ps, 8);
                l_i[i][r] = l_i[i][r] * corr + ps;
                #pragma unroll
                for (int dj = 0; dj < 4; ++dj) O[i][dj][r] *= corr;
            }
        }
        short8 ap[2][2], bv2[4][2];
        #pragma unroll
        for (int i = 0; i < 2; ++i)
            #pragma unroll
            for (int hh = 0; hh < 2; ++hh)
                ap[i][hh] = *(const short8*)&Ps[wave][16 * i + l16][hh * 32 + quad * 8];
        #pragma unroll
        for (int dj = 0; dj < 4; ++dj)
            #pragma unroll
            for (int hh = 0; hh < 2; ++hh)
                bv2[dj][hh] = *(const short8*)&Vs[16 * dj + l16][hh * 32 + quad * 8];
        #pragma unroll
        for (int i = 0; i < 2; ++i)
            #pragma unroll
            for (int dj = 0; dj < 4; ++dj) {
                O[i][dj] = __builtin_amdgcn_mfma_f32_16x16x32_bf16(ap[i][0], bv2[dj][0], O[i][dj], 0, 0, 0);
                O[i][dj] = __builtin_amdgcn_mfma_f32_16x16x32_bf16(ap[i][1], bv2[dj][1], O[i][dj], 0, 0, 0);
            }
    }
    bf16* og = out + ((size_t)b * SEQ + c * WIN) * D + h * HD;
    #pragma unroll
    for (int i = 0; i < 2; ++i) {
        #pragma unroll
        for (int r = 0; r < 4; ++r) {
            const float inv = 1.f / l_i[i][r];
            const int qq = qbase + 16 * i + quad * 4 + r;
            #pragma unroll
            for (int dj = 0; dj < 4; ++dj)
                og[(size_t)qq * D + 16 * dj + l16] = __float2bfloat16(O[i][dj][r] * inv);
        }
    }
}

// ---------------- fused residual add + LayerNorm (wave-per-row, vectorized) -------
template<int WBF>
__global__ __launch_bounds__(256)
void add_ln_kernel(const float* __restrict__ xin, const bf16* __restrict__ h,
                   float* __restrict__ xout, bf16* __restrict__ xbf,
                   const float* __restrict__ g, const float* __restrict__ beta)
{
    const int row  = blockIdx.x * 4 + (threadIdx.x >> 6);
    const int lane = threadIdx.x & 63;
    const float* xr = xin + (size_t)row * D;
    const unsigned short* hr = (const unsigned short*)h + (size_t)row * D;
    float t[12];
    float s = 0.f, s2 = 0.f;
    #pragma unroll
    for (int e = 0; e < 3; ++e) {
        const int i = lane * 4 + e * 256;
        const float4  xv = *(const float4*)(xr + i);
        const short4v hv = *(const short4v*)(hr + i);
        #pragma unroll
        for (int j = 0; j < 4; ++j) {
            const float tv = ((const float*)&xv)[j] + b2f(((const unsigned short*)&hv)[j]);
            t[e * 4 + j] = tv; s += tv; s2 += tv * tv;
        }
    }
    #pragma unroll
    for (int off = 1; off < 64; off <<= 1) {
        s  += __shfl_xor(s, off);
        s2 += __shfl_xor(s2, off);
    }
    const float mean = s * (1.f / D);
    const float inv  = rsqrtf(s2 * (1.f / D) - mean * mean + 1e-5f);
    #pragma unroll
    for (int e = 0; e < 3; ++e) {
        const int i = lane * 4 + e * 256;
        const float4 gv = *(const float4*)(g + i);
        const float4 bv = *(const float4*)(beta + i);
        float4 ov; short4v pb;
        #pragma unroll
        for (int j = 0; j < 4; ++j) {
            const float val = (t[e * 4 + j] - mean) * inv * ((const float*)&gv)[j]
                              + ((const float*)&bv)[j];
            ((float*)&ov)[j] = val;
            pb[j] = f2bs(val);
        }
        *(float4*)(xout + (size_t)row * D + i) = ov;
        if constexpr (WBF)
            *(short4v*)((short*)xbf + (size_t)row * D + i) = pb;
    }
}

// ---------------- host ------------------------------------------------------------
static void transpose_layer(const float* Wq, const float* Wk, const float* Wv,
                            const float* W1, const float* W2, int l,
                            bf16* wtl, hipStream_t stream)
{
    const size_t DDm = (size_t)D * D, DFFm = (size_t)D * FF;
    transpose_cvt<<<dim3(D / 32, D / 32), 256, 0, stream>>>(
        Wq + (size_t)l * DDm, wtl, D, D);
    transpose_cvt<<<dim3(D / 32, D / 32), 256, 0, stream>>>(
        Wk + (size_t)l * DDm, wtl + DDm, D, D);
    transpose_cvt<<<dim3(D / 32, D / 32), 256, 0, stream>>>(
        Wv + (size_t)l * DDm, wtl + 2 * DDm, D, D);
    transpose_cvt<<<dim3(FF / 32, D / 32), 256, 0, stream>>>(
        W1 + (size_t)l * DFFm, wtl + 3 * DDm, D, FF);
    transpose_cvt<<<dim3(D / 32, FF / 32), 256, 0, stream>>>(
        W2 + (size_t)l * DFFm, wtl + 3 * DDm + DFFm, FF, D);
}

static void run_fast8(const float* x0,
                      const float* Wq, const float* bq, const float* Wk, const float* bk,
                      const float* Wv, const float* bv, const float* W1, const float* b1,
                      const float* W2, const float* b2, const float* g1, const float* be1,
                      const float* g2, const float* be2, float* out,
                      bf16* qb, bf16* kb, bf16* vb, bf16* hb, bf16* mid, bf16* h2,
                      bf16* wt, bf16* xbf, bool hoisted, hipStream_t stream)
{
    const dim3 gQKV(64, 9);
    const dim3 gF1(64, 12);
    const dim3 gF2(64, 3);
    const dim3 ga(NC, NH, BATCH);
    const size_t DDm = (size_t)D * D, DFFm = (size_t)D * FF;
    const size_t LW = 3 * DDm + 2 * DFFm;
    const int SMEM = 131072;

    cvt_f32_bf16<<<NTOK * D / 2048, 256, 0, stream>>>(x0, xbf);
    if (hoisted)
        for (int l = 0; l < LAYERS; ++l)
            transpose_layer(Wq, Wk, Wv, W1, W2, l, wt + (size_t)l * LW, stream);

    for (int l = 0; l < LAYERS; ++l) {
        const float* xin = (l == 0) ? x0 : out;
        bf16* wtl = hoisted ? wt + (size_t)l * LW : wt;
        if (!hoisted)
            transpose_layer(Wq, Wk, Wv, W1, W2, l, wtl, stream);

        gemm8<3, 0><<<gQKV, 512, SMEM, stream>>>(
            xbf, wtl, bq + (size_t)l * D, bk + (size_t)l * D, bv + (size_t)l * D,
            qb, D, 2304);
        attn_mfma_kernel<<<ga, 256, 0, stream>>>(qb, kb, vb, hb);
        add_ln_kernel<1><<<NTOK / 4, 256, 0, stream>>>(xin, hb, out, xbf,
            g1 + (size_t)l * D, be1 + (size_t)l * D);
        gemm8<0, 1><<<gF1, 512, SMEM, stream>>>(
            xbf, wtl + 3 * DDm, b1 + (size_t)l * FF, nullptr, nullptr,
            mid, D, FF);
        gemm8<0, 0><<<gF2, 512, SMEM, stream>>>(
            mid, wtl + 3 * DDm + DFFm, b2 + (size_t)l * D, nullptr, nullptr,
            h2, FF, D);
        add_ln_kernel<1><<<NTOK / 4, 256, 0, stream>>>(out, h2, out, xbf,
            g2 + (size_t)l * D, be2 + (size_t)l * D);
    }
}

static void run_fast_old(const float* x0,
                         const float* Wq, const float* bq, const float* Wk, const float* bk,
                         const float* Wv, const float* bv, const float* W1, const float* b1,
                         const float* W2, const float* b2, const float* g1, const float* be1,
                         const float* g2, const float* be2, float* out,
                         bf16* qb, bf16* kb, bf16* vb, bf16* hb, bf16* mid, bf16* h2,
                         bf16* wt, bf16* xbf, hipStream_t stream)
{
    const dim3 gD(NTOK / 128, D / 128);
    const dim3 gF(NTOK / 128, FF / 128);
    const dim3 ga(NC, NH, BATCH);
    const size_t DDm = (size_t)D * D, DFFm = (size_t)D * FF;

    cvt_f32_bf16<<<NTOK * D / 2048, 256, 0, stream>>>(x0, xbf);
    for (int l = 0; l < LAYERS; ++l) {
        const float* xin = (l == 0) ? x0 : out;
        transpose_layer(Wq, Wk, Wv, W1, W2, l, wt, stream);

        mfma_gemm_bf<0, 1><<<gD, 256, 0, stream>>>(
            xbf, wt, bq + (size_t)l * D, qb, NTOK, D, D, 0.125f);
        mfma_gemm_bf<0, 1><<<gD, 256, 0, stream>>>(
            xbf, wt + DDm, bk + (size_t)l * D, kb, NTOK, D, D, 1.0f);
        mfma_gemm_bf<0, 2><<<gD, 256, 0, stream>>>(
            xbf, wt + 2 * DDm, bv + (size_t)l * D, vb, NTOK, D, D, 1.0f);
        attn_mfma_kernel<<<ga, 256, 0, stream>>>(qb, kb, vb, hb);
        add_ln_kernel<1><<<NTOK / 4, 256, 0, stream>>>(xin, hb, out, xbf,
            g1 + (size_t)l * D, be1 + (size_t)l * D);
        mfma_gemm_bf<1, 0><<<gF, 256, 0, stream>>>(
            xbf, wt + 3 * DDm, b1 + (size_t)l * FF, mid, NTOK, FF, D, 1.0f);
        mfma_gemm_bf<0, 0><<<gD, 256, 0, stream>>>(
            mid, wt + 3 * DDm + DFFm, b2 + (size_t)l * D, h2, NTOK, D, FF, 1.0f);
        add_ln_kernel<1><<<NTOK / 4, 256, 0, stream>>>(out, h2, out, xbf,
            g2 + (size_t)l * D, be2 + (size_t)l * D);
    }
}

extern "C" void kernel_launch(void* const* d_in, const int* in_sizes, int n_in,
                              void* d_out, int out_size, void* d_ws, size_t ws_size,
                              hipStream_t stream)
{
    const float* x0  = (const float*)d_in[0];
    const float* Wq  = (const float*)d_in[1];
    const float* bq  = (const float*)d_in[2];
    const float* Wk  = (const float*)d_in[3];
    const float* bk  = (const float*)d_in[4];
    const float* Wv  = (const float*)d_in[5];
    const float* bv  = (const float*)d_in[6];
    const float* W1  = (const float*)d_in[7];
    const float* b1  = (const float*)d_in[8];
    const float* W2  = (const float*)d_in[9];
    const float* b2  = (const float*)d_in[10];
    const float* g1  = (const float*)d_in[11];
    const float* be1 = (const float*)d_in[12];
    const float* g2  = (const float*)d_in[13];
    const float* be2 = (const float*)d_in[14];
    float* out = (float*)d_out;

    const size_t QE = (size_t)BATCH * NH * SEQ * HD;            // 12,582,912 elems
    const size_t LW = (size_t)3 * D * D + 2 * (size_t)D * FF;   // 6,488,064 elems
    bf16* qb  = (bf16*)d_ws;
    bf16* kb  = qb + QE;
    bf16* vb  = kb + QE;
    bf16* hb  = vb + QE;
    bf16* mid = qb;
    bf16* h2  = qb + 4 * QE;
    bf16* wt  = qb + 5 * QE;
    // tier A: hold all 4 layers' transposed weights (hoist transposes out of loop)
    const bool tierA = ws_size >= (6 * QE + (size_t)LAYERS * LW) * sizeof(bf16);
    const bool tierB = ws_size >= (6 * QE + LW) * sizeof(bf16);
    bf16* xbf = wt + (tierA ? (size_t)LAYERS * LW : LW);

    // one-time: allow 128 KiB dynamic LDS on the 8-phase GEMM
    static int attr_state = 0;
    if (attr_state == 0) {
        bool ok = true;
        ok &= hipFuncSetAttribute((const void*)(gemm8<3, 0>),
              hipFuncAttributeMaxDynamicSharedMemorySize, 131072) == hipSuccess;
        ok &= hipFuncSetAttribute((const void*)(gemm8<0, 1>),
              hipFuncAttributeMaxDynamicSharedMemorySize, 131072) == hipSuccess;
        ok &= hipFuncSetAttribute((const void*)(gemm8<0, 0>),
              hipFuncAttributeMaxDynamicSharedMemorySize, 131072) == hipSuccess;
        attr_state = ok ? 1 : -1;
    }

    if (tierB && attr_state == 1) {
        run_fast8(x0, Wq, bq, Wk, bk, Wv, bv, W1, b1, W2, b2, g1, be1, g2, be2,
                  out, qb, kb, vb, hb, mid, h2, wt, xbf, tierA, stream);
    } else if (tierB) {
        run_fast_old(x0, Wq, bq, Wk, bk, Wv, bv, W1, b1, W2, b2, g1, be1, g2, be2,
                     out, qb, kb, vb, hb, mid, h2, wt, xbf, stream);
    }
}

// Round 5
// 1612.057 us; speedup vs baseline: 1.0253x; 1.0253x over previous
//
#include <hip/hip_runtime.h>
#include <hip/hip_bf16.h>
#include <type_traits>

#define LAYERS 4
#define D      768
#define FF     3072
#define NH     12
#define HD     64
#define SEQ    4096
#define BATCH  4
#define WIN    128
#define NC     (SEQ / WIN)        // 32
#define NTOK   (BATCH * SEQ)      // 16384

using bf16 = __hip_bfloat16;
typedef short short8 __attribute__((ext_vector_type(8)));
typedef short short4v __attribute__((ext_vector_type(4)));
typedef float floatx4 __attribute__((ext_vector_type(4)));

__device__ __forceinline__ float b2f(unsigned short u) {
    return __uint_as_float(((unsigned)u) << 16);
}
__device__ __forceinline__ short f2bs(float f) {
    union { bf16 h; short s; } u; u.h = __float2bfloat16(f); return u.s;
}
__device__ __forceinline__ void st_cvt(float* p, float v) { *p = v; }
__device__ __forceinline__ void st_cvt(bf16* p, float v) { *p = __float2bfloat16(v); }

// async global->LDS, 16B per lane; LDS dest is wave-uniform base + lane*16
__device__ __forceinline__ void gl_lds16(const void* g, void* l) {
    __builtin_amdgcn_global_load_lds(
        (const __attribute__((address_space(1))) void*)g,
        (__attribute__((address_space(3))) void*)l, 16, 0, 0);
}

#define SB0   __builtin_amdgcn_sched_barrier(0)
#define BAR   __builtin_amdgcn_s_barrier()
#define VM4   asm volatile("s_waitcnt vmcnt(4)" ::: "memory")
#define VM0   asm volatile("s_waitcnt vmcnt(0)" ::: "memory")
#define SP1   __builtin_amdgcn_s_setprio(1)
#define SP0   __builtin_amdgcn_s_setprio(0)

// ---------------- f32 -> bf16 bulk convert (8 elems/thread) ----------------------
__global__ __launch_bounds__(256)
void cvt_f32_bf16(const float* __restrict__ src, bf16* __restrict__ dst)
{
    const int i = (blockIdx.x * 256 + threadIdx.x) * 8;
    const float4 a0 = *(const float4*)(src + i);
    const float4 a1 = *(const float4*)(src + i + 4);
    short8 p = { f2bs(a0.x), f2bs(a0.y), f2bs(a0.z), f2bs(a0.w),
                 f2bs(a1.x), f2bs(a1.y), f2bs(a1.z), f2bs(a1.w) };
    *(short8*)((short*)dst + i) = p;
}

// ---------------- weight transpose+convert: W[K][N] f32 -> WT[N][K] bf16 ----------
__global__ __launch_bounds__(256)
void transpose_cvt(const float* __restrict__ src, bf16* __restrict__ dst, int K, int N)
{
    __shared__ float t[32][33];
    const int n0 = blockIdx.x * 32, k0 = blockIdx.y * 32;
    const int tx = threadIdx.x & 31, ty = threadIdx.x >> 5;   // ty 0..7
    #pragma unroll
    for (int r = 0; r < 4; ++r)
        t[ty + 8 * r][tx] = src[(size_t)(k0 + ty + 8 * r) * N + n0 + tx];
    __syncthreads();
    #pragma unroll
    for (int r = 0; r < 4; ++r)
        dst[(size_t)(n0 + ty + 8 * r) * K + k0 + tx] = __float2bfloat16(t[tx][ty + 8 * r]);
}

// ================= 256x256 GEMM, 4 merged phases per 2-K-tile iteration ===========
// 512 threads = 8 waves (2M x 4N); per-wave output 128x64.
// LDS 128 KiB dynamic, XOR-swizzled (byte ^= (row&7)<<4) both sides (rule #21).
// Phase = {ds_reads | 1-2 stages | 2 MFMA quadrant clusters} + 1 barrier.
// Hazard proof (slot -> writer phase -> last-reader phase, barrier between):
//   A stages buf1-h1 (slot3): last read prev-D (D-end BAR).  B stages buf0-h0
//   (slot0): read in A (A-end BAR).  C stages buf0-h1 (slot1): read in A/B.
//   D stages buf1-h0 (slot2): read in C.  VM4 at B/D => any stage completes
//   before the barrier that releases its reader (checked incl. prologue).
// Second quadrant's reads + stage issue drain UNDER first quadrant's MFMAs
// (per-operand lgkmcnt, no intervening barrier) -- the round-4 lesson: the
// per-phase read->MFMA serialization was the cost, not the barriers per se.
template<int OMODE, int RELU>
__global__ __launch_bounds__(512, 2)
void gemm8(const bf16* __restrict__ A, const bf16* __restrict__ Wt,
           const float* __restrict__ b0, const float* __restrict__ b1p,
           const float* __restrict__ b2p, bf16* __restrict__ C,
           int K, int N)
{
    extern __shared__ char ldsc[];
    const int tid  = threadIdx.x;
    const int lane = tid & 63;
    const int wave = tid >> 6;
    const int quad = lane >> 4, l16 = lane & 15;
    const int wm = wave >> 2, wn = wave & 3;          // 2M x 4N wave grid

    // bijective XCD swizzle on M (gridDim.x == 64)
    const int bx  = blockIdx.x;
    const int bxs = (bx & 7) * 8 + (bx >> 3);
    const int row0 = bxs * 256;
    const int col0 = blockIdx.y * 256;

    // ---- staging address precompute (2 gl_lds per stage per thread) ----
    const int lin0 = wave * 1024 + lane * 16;         // e=0 dest byte in slot
    const int lin1 = 8192 + wave * 1024 + lane * 16;  // e=1
    const int rl0 = lin0 >> 7, rl1 = lin1 >> 7;       // local row 0..127
    const int so0 = (lin0 & 127) ^ ((rl0 & 7) << 4);  // pre-swizzled src offset
    const int so1 = (lin1 & 127) ^ ((rl1 & 7) << 4);
    const char* agl0 = (const char*)A  + 2 * ((size_t)(row0 + rl0) * K) + so0;
    const char* agl1 = (const char*)A  + 2 * ((size_t)(row0 + rl1) * K) + so1;
    const char* bgl0 = (const char*)Wt + 2 * ((size_t)(col0 + rl0) * K) + so0;
    const char* bgl1 = (const char*)Wt + 2 * ((size_t)(col0 + rl1) * K) + so1;
    const size_t hstr = (size_t)128 * K * 2;          // +128 rows

#define STA(d,h,kt) do { \
    gl_lds16(agl0 + ((h) ? hstr : 0) + (size_t)(kt) * 128, ldsc + ((d)*2+(h))*16384 + lin0); \
    gl_lds16(agl1 + ((h) ? hstr : 0) + (size_t)(kt) * 128, ldsc + ((d)*2+(h))*16384 + lin1); } while (0)
#define STB(d,h,kt) do { \
    gl_lds16(bgl0 + ((h) ? hstr : 0) + (size_t)(kt) * 128, ldsc + 65536 + ((d)*2+(h))*16384 + lin0); \
    gl_lds16(bgl1 + ((h) ? hstr : 0) + (size_t)(kt) * 128, ldsc + 65536 + ((d)*2+(h))*16384 + lin1); } while (0)

    // ---- fragment read precompute (XOR-swizzled ds_read_b128) ----
    const int arow  = wm * 64 + l16;
    const int abase = arow * 128;
    const int sA    = (arow & 7) << 4;
    const int aof0  = (quad * 16) ^ sA;
    const int aof1  = (64 + quad * 16) ^ sA;
    const int brow  = wn * 32 + l16;
    const int bbase = brow * 128;
    const int sB    = (brow & 7) << 4;
    const int bof0  = (quad * 16) ^ sB;
    const int bof1  = (64 + quad * 16) ^ sB;

    short8 af[4][2], bf0[2][2], bf1[2][2];
    floatx4 acc[2][2][4][2];
    const floatx4 zero = {0.f, 0.f, 0.f, 0.f};
    #pragma unroll
    for (int a = 0; a < 2; ++a)
        #pragma unroll
        for (int b = 0; b < 2; ++b)
            #pragma unroll
            for (int m = 0; m < 4; ++m)
                #pragma unroll
                for (int n = 0; n < 2; ++n) acc[a][b][m][n] = zero;

#define LDA(slot) do { const char* ab_ = ldsc + (slot)*16384 + abase; \
    _Pragma("unroll") for (int m_ = 0; m_ < 4; ++m_) { \
        af[m_][0] = *(const short8*)(ab_ + m_*2048 + aof0); \
        af[m_][1] = *(const short8*)(ab_ + m_*2048 + aof1); } } while (0)
#define LDB(slot, BF) do { const char* bb_ = ldsc + 65536 + (slot)*16384 + bbase; \
    _Pragma("unroll") for (int n_ = 0; n_ < 2; ++n_) { \
        BF[n_][0] = *(const short8*)(bb_ + n_*2048 + bof0); \
        BF[n_][1] = *(const short8*)(bb_ + n_*2048 + bof1); } } while (0)
#define MM(mh, nh, BF) do { \
    _Pragma("unroll") for (int m_ = 0; m_ < 4; ++m_) \
    _Pragma("unroll") for (int n_ = 0; n_ < 2; ++n_) { \
        acc[mh][nh][m_][n_] = __builtin_amdgcn_mfma_f32_16x16x32_bf16(af[m_][0], BF[n_][0], acc[mh][nh][m_][n_], 0, 0, 0); \
        acc[mh][nh][m_][n_] = __builtin_amdgcn_mfma_f32_16x16x32_bf16(af[m_][1], BF[n_][1], acc[mh][nh][m_][n_], 0, 0, 0); } } while (0)

    const int nkt   = K >> 6;    // 64-wide K-tiles
    const int niter = K >> 7;    // 2 tiles per iteration

    // ---- prologue: t0 full -> buf0, t1 A0/B0 -> buf1 ----
    STA(0,0,0); STB(0,0,0); STA(0,1,0); STB(0,1,0);
    STA(1,0,1); STB(1,0,1);
    VM4; SB0; BAR; SB0;

    for (int i = 0; i < niter; ++i) {
        const int k1 = 2*i + 1;
        const int k2 = (2*i + 2 < nkt) ? 2*i + 2 : nkt - 1;
        const int k3 = (2*i + 3 < nkt) ? 2*i + 3 : nkt - 1;
        // Phase A: buf0 quadrants (0,0)+(0,1) | stage buf1-h1 (tile k1)
        LDA(0); LDB(0, bf0); LDB(1, bf1); STA(1,1,k1); STB(1,1,k1);
        SP1; MM(0,0,bf0); MM(0,1,bf1); SP0; SB0; BAR; SB0;
        // Phase B: buf0 quadrants (1,0)+(1,1) | stage buf0-h0 (tile k2) | vmcnt
        LDA(1); STA(0,0,k2); STB(0,0,k2);
        SP1; MM(1,0,bf0); MM(1,1,bf1); SP0; VM4; SB0; BAR; SB0;
        // Phase C: buf1 quadrants (0,0)+(0,1) | stage buf0-h1 (tile k2)
        LDA(2); LDB(2, bf0); LDB(3, bf1); STA(0,1,k2); STB(0,1,k2);
        SP1; MM(0,0,bf0); MM(0,1,bf1); SP0; SB0; BAR; SB0;
        // Phase D: buf1 quadrants (1,0)+(1,1) | stage buf1-h0 (tile k3) | vmcnt
        LDA(3); STA(1,0,k3); STB(1,0,k3);
        SP1; MM(1,0,bf0); MM(1,1,bf1); SP0; VM4; SB0; BAR; SB0;
    }
    VM0;   // drain clamped prefetches before epilogue

#undef STA
#undef STB
#undef LDA
#undef LDB
#undef MM

    // ---- epilogue ----
    constexpr size_t QEc = (size_t)BATCH * NH * SEQ * HD;
    int sel = 0;
    const float* bptr = b0;
    float scl = 1.0f;
    int ccb = col0;
    if constexpr (OMODE == 3) {
        sel  = blockIdx.y / 3;                 // 0=Q 1=K 2=V (uniform per block)
        bptr = (sel == 0) ? b0 : (sel == 1) ? b1p : b2p;
        scl  = (sel == 0) ? 0.125f : 1.0f;
        ccb  = col0 - sel * 768;
    }
    #pragma unroll
    for (int mh = 0; mh < 2; ++mh)
    #pragma unroll
    for (int nh = 0; nh < 2; ++nh)
    #pragma unroll
    for (int n = 0; n < 2; ++n) {
        const int c  = ccb + nh * 128 + wn * 32 + n * 16 + l16;
        const float bvv = bptr[c];
        #pragma unroll
        for (int m = 0; m < 4; ++m) {
            const int rr0 = row0 + mh * 128 + wm * 64 + m * 16 + quad * 4;
            if constexpr (OMODE == 3) {
                if (sel == 2) {
                    short4v pack;
                    #pragma unroll
                    for (int r = 0; r < 4; ++r)
                        pack[r] = f2bs(acc[mh][nh][m][n][r] + bvv);
                    const int b_ = rr0 >> 12, s_ = rr0 & (SEQ - 1);
                    const int h_ = c >> 6, d_ = c & (HD - 1);
                    bf16* Cv = C + 2 * QEc;
                    *(short4v*)&Cv[(((size_t)(b_ * NH + h_)) * HD + d_) * SEQ + s_] = pack;
                } else {
                    bf16* Cq = C + (size_t)sel * QEc;
                    #pragma unroll
                    for (int r = 0; r < 4; ++r) {
                        const float v = (acc[mh][nh][m][n][r] + bvv) * scl;
                        const int rr = rr0 + r;
                        const int b_ = rr >> 12, s_ = rr & (SEQ - 1);
                        const int h_ = c >> 6, d_ = c & (HD - 1);
                        Cq[(((size_t)(b_ * NH + h_)) * SEQ + s_) * HD + d_] = __float2bfloat16(v);
                    }
                }
            } else {
                #pragma unroll
                for (int r = 0; r < 4; ++r) {
                    float v = acc[mh][nh][m][n][r] + bvv;
                    if (RELU) v = fmaxf(v, 0.f);
                    C[(size_t)(rr0 + r) * N + c] = __float2bfloat16(v);
                }
            }
        }
    }
}

// ---------------- round-1 fast MFMA GEMM (fallback if dyn-LDS attr fails) ---------
template<int RELU, int OMODE>
__global__ __launch_bounds__(256)
void mfma_gemm_bf(const bf16* __restrict__ A, const bf16* __restrict__ Wt,
                  const float* __restrict__ bias, bf16* __restrict__ C,
                  int M, int N, int K, float scale)
{
    __shared__ __align__(16) short As[128 * 32];
    __shared__ __align__(16) short Bs[128 * 32];
    const int tid  = threadIdx.x;
    const int lane = tid & 63;
    const int wave = tid >> 6;
    const int quad = lane >> 4, l16 = lane & 15;
    const int mw = (wave >> 1) * 64, nw = (wave & 1) * 64;
    const int row0 = blockIdx.x * 128;
    const int col0 = blockIdx.y * 128;

    const unsigned short* Ag = (const unsigned short*)A;
    const unsigned short* Bg = (const unsigned short*)Wt;
    const int sr = lane >> 2;
    const int sc = (lane & 3) * 8;

    floatx4 acc[4][4];
    const floatx4 zero = {0.f, 0.f, 0.f, 0.f};
    #pragma unroll
    for (int i = 0; i < 4; ++i)
        #pragma unroll
        for (int j = 0; j < 4; ++j) acc[i][j] = zero;

    const size_t abase = (size_t)row0 * K;
    const size_t bbase = (size_t)col0 * K;

    for (int k0 = 0; k0 < K; k0 += 32) {
        __syncthreads();
        #pragma unroll
        for (int e = 0; e < 2; ++e) {
            const int seg = wave * 2 + e;
            const int r = seg * 16 + sr;
            gl_lds16(Ag + abase + (size_t)r * K + k0 + sc, &As[seg * 512]);
            gl_lds16(Bg + bbase + (size_t)r * K + k0 + sc, &Bs[seg * 512]);
        }
        __syncthreads();
        short8 af[4], bfr[4];
        #pragma unroll
        for (int i = 0; i < 4; ++i)
            af[i] = *(const short8*)&As[(mw + 16 * i + l16) * 32 + quad * 8];
        #pragma unroll
        for (int j = 0; j < 4; ++j)
            bfr[j] = *(const short8*)&Bs[(nw + 16 * j + l16) * 32 + quad * 8];
        #pragma unroll
        for (int i = 0; i < 4; ++i)
            #pragma unroll
            for (int j = 0; j < 4; ++j)
                acc[i][j] = __builtin_amdgcn_mfma_f32_16x16x32_bf16(af[i], bfr[j], acc[i][j], 0, 0, 0);
    }
    #pragma unroll
    for (int j = 0; j < 4; ++j) {
        const int c = col0 + nw + 16 * j + l16;
        const float bv = bias[c];
        #pragma unroll
        for (int i = 0; i < 4; ++i) {
            const int rr0 = row0 + mw + 16 * i + quad * 4;
            if constexpr (OMODE == 2) {
                short4v pack;
                #pragma unroll
                for (int r = 0; r < 4; ++r)
                    pack[r] = f2bs((acc[i][j][r] + bv) * scale);
                const int b_ = rr0 >> 12, s_ = rr0 & (SEQ - 1);
                const int h_ = c >> 6, d_ = c & (HD - 1);
                *(short4v*)&C[(((size_t)(b_ * NH + h_)) * HD + d_) * SEQ + s_] = pack;
            } else {
                #pragma unroll
                for (int r = 0; r < 4; ++r) {
                    float v = acc[i][j][r] + bv;
                    if (RELU) v = fmaxf(v, 0.f);
                    v *= scale;
                    const int rr = rr0 + r;
                    if constexpr (OMODE == 1) {
                        const int b_ = rr >> 12, s_ = rr & (SEQ - 1);
                        const int h_ = c >> 6, d_ = c & (HD - 1);
                        st_cvt(&C[(((size_t)(b_ * NH + h_)) * SEQ + s_) * HD + d_], v);
                    } else {
                        st_cvt(&C[(size_t)rr * N + c], v);
                    }
                }
            }
        }
    }
}

// ---------------- MFMA sliding-window flash attention ----------------------------
__global__ __launch_bounds__(256, 2)
void attn_mfma_kernel(const bf16* __restrict__ q, const bf16* __restrict__ k,
                      const bf16* __restrict__ v, bf16* __restrict__ out)
{
    __shared__ __align__(16) short Qs[128][72];     // [q][d]
    __shared__ __align__(16) short Ks[64][72];      // [key][d]
    __shared__ __align__(16) short Vs[64][72];      // [d][key]  (V^T)
    __shared__ __align__(16) short Ps[4][32][72];   // per-wave P [q][key]

    const int c = blockIdx.x, h = blockIdx.y, b = blockIdx.z;
    const int tid = threadIdx.x;
    const int wave = tid >> 6, lane = tid & 63;
    const int quad = lane >> 4, l16 = lane & 15;
    const int qbase = wave * 32;

    const unsigned short* qg = (const unsigned short*)q + ((size_t)(b * NH + h)) * SEQ * HD;
    const unsigned short* kg = (const unsigned short*)k + ((size_t)(b * NH + h)) * SEQ * HD;
    const unsigned short* vg = (const unsigned short*)v + ((size_t)(b * NH + h)) * HD * SEQ;

    #pragma unroll
    for (int e = 0; e < 4; ++e) {
        const int idx = tid + e * 256;
        const int row = idx >> 3, d0 = (idx & 7) * 8;
        *(uint4*)&Qs[row][d0] = *(const uint4*)(qg + (size_t)(c * WIN + row) * HD + d0);
    }

    floatx4 O[2][4];
    const floatx4 zero = {0.f, 0.f, 0.f, 0.f};
    float m_i[2][4], l_i[2][4];
    #pragma unroll
    for (int i = 0; i < 2; ++i)
        #pragma unroll
        for (int r = 0; r < 4; ++r) { m_i[i][r] = -1e30f; l_i[i][r] = 0.f; }
    #pragma unroll
    for (int i = 0; i < 2; ++i)
        #pragma unroll
        for (int dj = 0; dj < 4; ++dj) O[i][dj] = zero;

    for (int sl = 0; sl < 6; ++sl) {
        const int s0 = sl * 64;
        const int kpos0 = c * WIN - WIN + s0;
        if (kpos0 < 0 || kpos0 >= SEQ) continue;
        __syncthreads();
        #pragma unroll
        for (int e = 0; e < 2; ++e) {
            const int idx = tid + e * 256;
            const int row = idx >> 3, d0 = (idx & 7) * 8;
            *(uint4*)&Ks[row][d0] = *(const uint4*)(kg + (size_t)(kpos0 + row) * HD + d0);
            *(uint4*)&Vs[row][d0] = *(const uint4*)(vg + (size_t)row * SEQ + kpos0 + d0);
        }
        __syncthreads();
        short8 aq[2][2], bk2[4][2];
        #pragma unroll
        for (int i = 0; i < 2; ++i)
            #pragma unroll
            for (int hh = 0; hh < 2; ++hh)
                aq[i][hh] = *(const short8*)&Qs[qbase + 16 * i + l16][hh * 32 + quad * 8];
        #pragma unroll
        for (int j = 0; j < 4; ++j)
            #pragma unroll
            for (int hh = 0; hh < 2; ++hh)
                bk2[j][hh] = *(const short8*)&Ks[16 * j + l16][hh * 32 + quad * 8];
        floatx4 sc[2][4];
        #pragma unroll
        for (int i = 0; i < 2; ++i)
            #pragma unroll
            for (int j = 0; j < 4; ++j) {
                floatx4 t = __builtin_amdgcn_mfma_f32_16x16x32_bf16(aq[i][0], bk2[j][0], zero, 0, 0, 0);
                sc[i][j]  = __builtin_amdgcn_mfma_f32_16x16x32_bf16(aq[i][1], bk2[j][1], t, 0, 0, 0);
            }
        #pragma unroll
        for (int i = 0; i < 2; ++i) {
            #pragma unroll
            for (int r = 0; r < 4; ++r) {
                const int qq = qbase + 16 * i + quad * 4 + r;
                float sv[4];
                float mx = -1e30f;
                #pragma unroll
                for (int j = 0; j < 4; ++j) {
                    const int kj = s0 + 16 * j + l16;
                    const bool ok = (kj >= qq) && (kj <= qq + 2 * WIN);
                    const float s = ok ? sc[i][j][r] : -1e30f;
                    sv[j] = s;
                    mx = fmaxf(mx, s);
                }
                mx = fmaxf(mx, __shfl_xor(mx, 1));
                mx = fmaxf(mx, __shfl_xor(mx, 2));
                mx = fmaxf(mx, __shfl_xor(mx, 4));
                mx = fmaxf(mx, __shfl_xor(mx, 8));
                const float mn = fmaxf(m_i[i][r], mx);
                const float corr = __expf(m_i[i][r] - mn);
                m_i[i][r] = mn;
                float ps = 0.f;
                #pragma unroll
                for (int j = 0; j < 4; ++j) {
                    const float p = (sv[j] > -0.9e30f) ? __expf(sv[j] - mn) : 0.f;
                    ps += p;
                    Ps[wave][16 * i + quad * 4 + r][16 * j + l16] = f2bs(p);
                }
                ps += __shfl_xor(ps, 1);
                ps += __shfl_xor(ps, 2);
                ps += __shfl_xor(ps, 4);
                ps += __shfl_xor(ps, 8);
                l_i[i][r] = l_i[i][r] * corr + ps;
                #pragma unroll
                for (int dj = 0; dj < 4; ++dj) O[i][dj][r] *= corr;
            }
        }
        short8 ap[2][2], bv2[4][2];
        #pragma unroll
        for (int i = 0; i < 2; ++i)
            #pragma unroll
            for (int hh = 0; hh < 2; ++hh)
                ap[i][hh] = *(const short8*)&Ps[wave][16 * i + l16][hh * 32 + quad * 8];
        #pragma unroll
        for (int dj = 0; dj < 4; ++dj)
            #pragma unroll
            for (int hh = 0; hh < 2; ++hh)
                bv2[dj][hh] = *(const short8*)&Vs[16 * dj + l16][hh * 32 + quad * 8];
        #pragma unroll
        for (int i = 0; i < 2; ++i)
            #pragma unroll
            for (int dj = 0; dj < 4; ++dj) {
                O[i][dj] = __builtin_amdgcn_mfma_f32_16x16x32_bf16(ap[i][0], bv2[dj][0], O[i][dj], 0, 0, 0);
                O[i][dj] = __builtin_amdgcn_mfma_f32_16x16x32_bf16(ap[i][1], bv2[dj][1], O[i][dj], 0, 0, 0);
            }
    }
    bf16* og = out + ((size_t)b * SEQ + c * WIN) * D + h * HD;
    #pragma unroll
    for (int i = 0; i < 2; ++i) {
        #pragma unroll
        for (int r = 0; r < 4; ++r) {
            const float inv = 1.f / l_i[i][r];
            const int qq = qbase + 16 * i + quad * 4 + r;
            #pragma unroll
            for (int dj = 0; dj < 4; ++dj)
                og[(size_t)qq * D + 16 * dj + l16] = __float2bfloat16(O[i][dj][r] * inv);
        }
    }
}

// ---------------- fused residual add + LayerNorm (wave-per-row, vectorized) -------
template<int WBF>
__global__ __launch_bounds__(256)
void add_ln_kernel(const float* __restrict__ xin, const bf16* __restrict__ h,
                   float* __restrict__ xout, bf16* __restrict__ xbf,
                   const float* __restrict__ g, const float* __restrict__ beta)
{
    const int row  = blockIdx.x * 4 + (threadIdx.x >> 6);
    const int lane = threadIdx.x & 63;
    const float* xr = xin + (size_t)row * D;
    const unsigned short* hr = (const unsigned short*)h + (size_t)row * D;
    float t[12];
    float s = 0.f, s2 = 0.f;
    #pragma unroll
    for (int e = 0; e < 3; ++e) {
        const int i = lane * 4 + e * 256;
        const float4  xv = *(const float4*)(xr + i);
        const short4v hv = *(const short4v*)(hr + i);
        #pragma unroll
        for (int j = 0; j < 4; ++j) {
            const float tv = ((const float*)&xv)[j] + b2f(((const unsigned short*)&hv)[j]);
            t[e * 4 + j] = tv; s += tv; s2 += tv * tv;
        }
    }
    #pragma unroll
    for (int off = 1; off < 64; off <<= 1) {
        s  += __shfl_xor(s, off);
        s2 += __shfl_xor(s2, off);
    }
    const float mean = s * (1.f / D);
    const float inv  = rsqrtf(s2 * (1.f / D) - mean * mean + 1e-5f);
    #pragma unroll
    for (int e = 0; e < 3; ++e) {
        const int i = lane * 4 + e * 256;
        const float4 gv = *(const float4*)(g + i);
        const float4 bv = *(const float4*)(beta + i);
        float4 ov; short4v pb;
        #pragma unroll
        for (int j = 0; j < 4; ++j) {
            const float val = (t[e * 4 + j] - mean) * inv * ((const float*)&gv)[j]
                              + ((const float*)&bv)[j];
            ((float*)&ov)[j] = val;
            pb[j] = f2bs(val);
        }
        *(float4*)(xout + (size_t)row * D + i) = ov;
        if constexpr (WBF)
            *(short4v*)((short*)xbf + (size_t)row * D + i) = pb;
    }
}

// ---------------- host ------------------------------------------------------------
static void transpose_layer(const float* Wq, const float* Wk, const float* Wv,
                            const float* W1, const float* W2, int l,
                            bf16* wtl, hipStream_t stream)
{
    const size_t DDm = (size_t)D * D, DFFm = (size_t)D * FF;
    transpose_cvt<<<dim3(D / 32, D / 32), 256, 0, stream>>>(
        Wq + (size_t)l * DDm, wtl, D, D);
    transpose_cvt<<<dim3(D / 32, D / 32), 256, 0, stream>>>(
        Wk + (size_t)l * DDm, wtl + DDm, D, D);
    transpose_cvt<<<dim3(D / 32, D / 32), 256, 0, stream>>>(
        Wv + (size_t)l * DDm, wtl + 2 * DDm, D, D);
    transpose_cvt<<<dim3(FF / 32, D / 32), 256, 0, stream>>>(
        W1 + (size_t)l * DFFm, wtl + 3 * DDm, D, FF);
    transpose_cvt<<<dim3(D / 32, FF / 32), 256, 0, stream>>>(
        W2 + (size_t)l * DFFm, wtl + 3 * DDm + DFFm, FF, D);
}

static void run_fast8(const float* x0,
                      const float* Wq, const float* bq, const float* Wk, const float* bk,
                      const float* Wv, const float* bv, const float* W1, const float* b1,
                      const float* W2, const float* b2, const float* g1, const float* be1,
                      const float* g2, const float* be2, float* out,
                      bf16* qb, bf16* kb, bf16* vb, bf16* hb, bf16* mid, bf16* h2,
                      bf16* wt, bf16* xbf, bool hoisted, hipStream_t stream)
{
    const dim3 gQKV(64, 9);
    const dim3 gF1(64, 12);
    const dim3 gF2(64, 3);
    const dim3 ga(NC, NH, BATCH);
    const size_t DDm = (size_t)D * D, DFFm = (size_t)D * FF;
    const size_t LW = 3 * DDm + 2 * DFFm;
    const int SMEM = 131072;

    cvt_f32_bf16<<<NTOK * D / 2048, 256, 0, stream>>>(x0, xbf);
    if (hoisted)
        for (int l = 0; l < LAYERS; ++l)
            transpose_layer(Wq, Wk, Wv, W1, W2, l, wt + (size_t)l * LW, stream);

    for (int l = 0; l < LAYERS; ++l) {
        const float* xin = (l == 0) ? x0 : out;
        bf16* wtl = hoisted ? wt + (size_t)l * LW : wt;
        if (!hoisted)
            transpose_layer(Wq, Wk, Wv, W1, W2, l, wtl, stream);

        gemm8<3, 0><<<gQKV, 512, SMEM, stream>>>(
            xbf, wtl, bq + (size_t)l * D, bk + (size_t)l * D, bv + (size_t)l * D,
            qb, D, 2304);
        attn_mfma_kernel<<<ga, 256, 0, stream>>>(qb, kb, vb, hb);
        add_ln_kernel<1><<<NTOK / 4, 256, 0, stream>>>(xin, hb, out, xbf,
            g1 + (size_t)l * D, be1 + (size_t)l * D);
        gemm8<0, 1><<<gF1, 512, SMEM, stream>>>(
            xbf, wtl + 3 * DDm, b1 + (size_t)l * FF, nullptr, nullptr,
            mid, D, FF);
        gemm8<0, 0><<<gF2, 512, SMEM, stream>>>(
            mid, wtl + 3 * DDm + DFFm, b2 + (size_t)l * D, nullptr, nullptr,
            h2, FF, D);
        add_ln_kernel<1><<<NTOK / 4, 256, 0, stream>>>(out, h2, out, xbf,
            g2 + (size_t)l * D, be2 + (size_t)l * D);
    }
}

static void run_fast_old(const float* x0,
                         const float* Wq, const float* bq, const float* Wk, const float* bk,
                         const float* Wv, const float* bv, const float* W1, const float* b1,
                         const float* W2, const float* b2, const float* g1, const float* be1,
                         const float* g2, const float* be2, float* out,
                         bf16* qb, bf16* kb, bf16* vb, bf16* hb, bf16* mid, bf16* h2,
                         bf16* wt, bf16* xbf, hipStream_t stream)
{
    const dim3 gD(NTOK / 128, D / 128);
    const dim3 gF(NTOK / 128, FF / 128);
    const dim3 ga(NC, NH, BATCH);
    const size_t DDm = (size_t)D * D, DFFm = (size_t)D * FF;

    cvt_f32_bf16<<<NTOK * D / 2048, 256, 0, stream>>>(x0, xbf);
    for (int l = 0; l < LAYERS; ++l) {
        const float* xin = (l == 0) ? x0 : out;
        transpose_layer(Wq, Wk, Wv, W1, W2, l, wt, stream);

        mfma_gemm_bf<0, 1><<<gD, 256, 0, stream>>>(
            xbf, wt, bq + (size_t)l * D, qb, NTOK, D, D, 0.125f);
        mfma_gemm_bf<0, 1><<<gD, 256, 0, stream>>>(
            xbf, wt + DDm, bk + (size_t)l * D, kb, NTOK, D, D, 1.0f);
        mfma_gemm_bf<0, 2><<<gD, 256, 0, stream>>>(
            xbf, wt + 2 * DDm, bv + (size_t)l * D, vb, NTOK, D, D, 1.0f);
        attn_mfma_kernel<<<ga, 256, 0, stream>>>(qb, kb, vb, hb);
        add_ln_kernel<1><<<NTOK / 4, 256, 0, stream>>>(xin, hb, out, xbf,
            g1 + (size_t)l * D, be1 + (size_t)l * D);
        mfma_gemm_bf<1, 0><<<gF, 256, 0, stream>>>(
            xbf, wt + 3 * DDm, b1 + (size_t)l * FF, mid, NTOK, FF, D, 1.0f);
        mfma_gemm_bf<0, 0><<<gD, 256, 0, stream>>>(
            mid, wt + 3 * DDm + DFFm, b2 + (size_t)l * D, h2, NTOK, D, FF, 1.0f);
        add_ln_kernel<1><<<NTOK / 4, 256, 0, stream>>>(out, h2, out, xbf,
            g2 + (size_t)l * D, be2 + (size_t)l * D);
    }
}

extern "C" void kernel_launch(void* const* d_in, const int* in_sizes, int n_in,
                              void* d_out, int out_size, void* d_ws, size_t ws_size,
                              hipStream_t stream)
{
    const float* x0  = (const float*)d_in[0];
    const float* Wq  = (const float*)d_in[1];
    const float* bq  = (const float*)d_in[2];
    const float* Wk  = (const float*)d_in[3];
    const float* bk  = (const float*)d_in[4];
    const float* Wv  = (const float*)d_in[5];
    const float* bv  = (const float*)d_in[6];
    const float* W1  = (const float*)d_in[7];
    const float* b1  = (const float*)d_in[8];
    const float* W2  = (const float*)d_in[9];
    const float* b2  = (const float*)d_in[10];
    const float* g1  = (const float*)d_in[11];
    const float* be1 = (const float*)d_in[12];
    const float* g2  = (const float*)d_in[13];
    const float* be2 = (const float*)d_in[14];
    float* out = (float*)d_out;

    const size_t QE = (size_t)BATCH * NH * SEQ * HD;            // 12,582,912 elems
    const size_t LW = (size_t)3 * D * D + 2 * (size_t)D * FF;   // 6,488,064 elems
    bf16* qb  = (bf16*)d_ws;
    bf16* kb  = qb + QE;
    bf16* vb  = kb + QE;
    bf16* hb  = vb + QE;
    bf16* mid = qb;
    bf16* h2  = qb + 4 * QE;
    bf16* wt  = qb + 5 * QE;
    // tier A: hold all 4 layers' transposed weights (hoist transposes out of loop)
    const bool tierA = ws_size >= (6 * QE + (size_t)LAYERS * LW) * sizeof(bf16);
    const bool tierB = ws_size >= (6 * QE + LW) * sizeof(bf16);
    bf16* xbf = wt + (tierA ? (size_t)LAYERS * LW : LW);

    // one-time: allow 128 KiB dynamic LDS on the 4-phase GEMM
    static int attr_state = 0;
    if (attr_state == 0) {
        bool ok = true;
        ok &= hipFuncSetAttribute((const void*)(gemm8<3, 0>),
              hipFuncAttributeMaxDynamicSharedMemorySize, 131072) == hipSuccess;
        ok &= hipFuncSetAttribute((const void*)(gemm8<0, 1>),
              hipFuncAttributeMaxDynamicSharedMemorySize, 131072) == hipSuccess;
        ok &= hipFuncSetAttribute((const void*)(gemm8<0, 0>),
              hipFuncAttributeMaxDynamicSharedMemorySize, 131072) == hipSuccess;
        attr_state = ok ? 1 : -1;
    }

    if (tierB && attr_state == 1) {
        run_fast8(x0, Wq, bq, Wk, bk, Wv, bv, W1, b1, W2, b2, g1, be1, g2, be2,
                  out, qb, kb, vb, hb, mid, h2, wt, xbf, tierA, stream);
    } else if (tierB) {
        run_fast_old(x0, Wq, bq, Wk, bk, Wv, bv, W1, b1, W2, b2, g1, be1, g2, be2,
                     out, qb, kb, vb, hb, mid, h2, wt, xbf, stream);
    }
}